// Round 6
// baseline (612.676 us; speedup 1.0000x reference)
//
#include <hip/hip_runtime.h>
#include <hip/hip_bf16.h>

typedef __attribute__((ext_vector_type(8))) short short8;
typedef __attribute__((ext_vector_type(4))) short s16x4;
typedef __attribute__((ext_vector_type(4))) float f32x4;
typedef unsigned short u16;

#define DEV __device__ __forceinline__
#define MFMA32(a, b, c) __builtin_amdgcn_mfma_f32_16x16x32_bf16(a, b, c, 0, 0, 0)
#define MFMA16(a, b, c) __builtin_amdgcn_mfma_f32_16x16x16bf16_1k(a, b, c, 0, 0, 0)
#define SBAR() asm volatile("s_barrier" ::: "memory")

DEV u16 f2b(float f) {
    __hip_bfloat16 h = __float2bfloat16(f);
    return __builtin_bit_cast(unsigned short, h);
}

DEV float max3f(float a, float b, float c) {
    float d;
    asm("v_max3_f32 %0, %1, %2, %3" : "=v"(d) : "v"(a), "v"(b), "v"(c));
    return d;
}

DEV void gl_lds16(const u16* g, u16* l) {
    __builtin_amdgcn_global_load_lds((const unsigned int*)g, (unsigned int*)l, 16, 0, 0);
}

// ---------------- cast x: fp32 -> bf16 ----------------
__global__ __launch_bounds__(256) void cast_bf16(const float* __restrict__ in, u16* __restrict__ out, int n) {
    int i = (blockIdx.x * 256 + threadIdx.x) * 4;
    if (i < n) {
        float4 v = *(const float4*)(in + i);
        ushort4 o;
        o.x = f2b(v.x); o.y = f2b(v.y); o.z = f2b(v.z); o.w = f2b(v.w);
        *(ushort4*)(out + i) = o;
    }
}

// ---------------- transpose + cast: W[R][C] fp32 -> Wt[C][R] bf16 ----------------
__global__ __launch_bounds__(256) void transpose_cast(const float* __restrict__ in, u16* __restrict__ out,
                                                      int R, int C) {
    __shared__ float t[32][33];
    int bx = blockIdx.x * 32;
    int by = blockIdx.y * 32;
    int tx = threadIdx.x, ty = threadIdx.y;  // (32, 8)
#pragma unroll
    for (int i = 0; i < 32; i += 8) t[ty + i][tx] = in[(size_t)(by + ty + i) * C + bx + tx];
    __syncthreads();
#pragma unroll
    for (int i = 0; i < 32; i += 8) out[(size_t)(bx + ty + i) * R + by + tx] = f2b(t[tx][ty + i]);
}

// ---------------- pack biases into one buffer ----------------
__global__ __launch_bounds__(256) void pack_bias(const float* __restrict__ bq, const float* __restrict__ bk,
                                                 const float* __restrict__ bv, const float* __restrict__ bo,
                                                 const float* __restrict__ b1, const float* __restrict__ b2,
                                                 float* __restrict__ out) {
    int i = blockIdx.x * 256 + threadIdx.x;
    if (i >= 9216) return;
    float v;
    if (i < 1024) v = bq[i];
    else if (i < 2048) v = bk[i - 1024];
    else if (i < 3072) v = bv[i - 2048];
    else if (i < 4096) v = bo[i - 3072];
    else if (i < 8192) v = b1[i - 4096];
    else v = b2[i - 8192];
    out[i] = v;
}

// ---------------- GEMM: 256x128 tile, BK=64, TRIPLE-buffered, spread staging ----------------
// 512 threads = 8 waves (2M x 4N). G4 swizzle both-sides (chunk^=row&7).
// Per K-tile: 3 half-tiles staged one-per-phase (q0 -> (t+1,B), q1/q2 -> (t+2,A0/A1)),
// counted vmcnt(4) per tile (2 half-tiles in flight), vmcnt(0) only at last tile.
// Tri-buffer makes the 1.67-tile lead race-free. C[M][N] = A[M][K]*Bt[N][K]^T.
template <bool GELU, bool BF16OUT>
__global__ __launch_bounds__(512, 2) void gemm8p(const u16* __restrict__ A, const u16* __restrict__ B,
                                                 const float* __restrict__ bias, float* __restrict__ cf,
                                                 u16* __restrict__ cb, int M, int N, int K) {
    __shared__ __align__(16) u16 As[3][256 * 64];
    __shared__ __align__(16) u16 Bs[3][128 * 64];

    const int tid = threadIdx.x;
    const int wid = tid >> 6, lane = tid & 63;
    const int wm = wid >> 2, wn = wid & 3;
    const int r16 = lane & 15, g = lane >> 4;
    const int sw = r16 & 7;

    // XCD-aware swizzle of 1-D grid (gridDim.x divisible by 8)
    const int nwg = gridDim.x;
    const int mtiles = M >> 8;
    const int sid = (blockIdx.x & 7) * (nwg >> 3) + (blockIdx.x >> 3);
    const int bm = sid % mtiles, bn = sid / mtiles;

    // staging: thread tid covers 16B chunk (row=tid>>3 (+64j), chunk=tid&7); source inverse-swizzled
    const int srow = tid >> 3;
    const int schunk = (tid & 7) ^ (srow & 7);
    const u16* ga = A + (size_t)(bm * 256 + srow) * K + schunk * 8;
    const u16* gb = B + (size_t)(bn * 128 + srow) * K + schunk * 8;

    const int NT = K >> 6;

    auto STAGE = [&](int tau, int ih) {
        if (tau >= NT) return;
        const int bb = tau % 3;
        const int kn = tau << 6;
        if (ih == 0) {          // A rows 0-127
            gl_lds16(ga + kn, &As[bb][wid * 512]);
            gl_lds16(ga + (size_t)64 * K + kn, &As[bb][wid * 512 + 4096]);
        } else if (ih == 1) {   // A rows 128-255
            gl_lds16(ga + (size_t)128 * K + kn, &As[bb][wid * 512 + 8192]);
            gl_lds16(ga + (size_t)192 * K + kn, &As[bb][wid * 512 + 12288]);
        } else {                // B rows 0-127
            gl_lds16(gb + kn, &Bs[bb][wid * 512]);
            gl_lds16(gb + (size_t)64 * K + kn, &Bs[bb][wid * 512 + 4096]);
        }
    };

    f32x4 acc[16];
#pragma unroll
    for (int i = 0; i < 16; i++) acc[i] = (f32x4){0.f, 0.f, 0.f, 0.f};

    // prologue: tile0 complete + tile1 A-halves (5 half-tiles, 10 loads)
    STAGE(0, 0); STAGE(0, 1); STAGE(0, 2);
    STAGE(1, 0); STAGE(1, 1);

    for (int t = 0; t < NT; ++t) {
        const int c = t % 3;
        if (t == NT - 1) asm volatile("s_waitcnt vmcnt(0)" ::: "memory");
        else             asm volatile("s_waitcnt vmcnt(4)" ::: "memory");
        SBAR();

        short8 bfr[2][2];
#pragma unroll
        for (int q = 0; q < 4; q++) {
            if (q == 0) {
#pragma unroll
                for (int n = 0; n < 2; n++)
#pragma unroll
                    for (int ks = 0; ks < 2; ks++) {
                        int row = wn * 32 + n * 16 + r16;
                        int off = row * 128 + (((ks * 4 + g) ^ sw) * 16);
                        bfr[n][ks] = *(const short8*)((const char*)&Bs[c][0] + off);
                    }
            }
            short8 af[2][2];
#pragma unroll
            for (int mm = 0; mm < 2; mm++)
#pragma unroll
                for (int ks = 0; ks < 2; ks++) {
                    int row = wm * 128 + (q * 2 + mm) * 16 + r16;
                    int off = row * 128 + (((ks * 4 + g) ^ sw) * 16);
                    af[mm][ks] = *(const short8*)((const char*)&As[c][0] + off);
                }
            // spread staging: one half-tile per phase (none in phase 3)
            if (q == 0) STAGE(t + 1, 2);
            else if (q < 3) STAGE(t + 2, q - 1);

            asm volatile("s_waitcnt lgkmcnt(0)" ::: "memory");
            __builtin_amdgcn_s_setprio(1);
#pragma unroll
            for (int mm = 0; mm < 2; mm++)
#pragma unroll
                for (int n = 0; n < 2; n++)
#pragma unroll
                    for (int ks = 0; ks < 2; ks++)
                        acc[(q * 2 + mm) * 2 + n] = MFMA32(af[mm][ks], bfr[n][ks], acc[(q * 2 + mm) * 2 + n]);
            __builtin_amdgcn_s_setprio(0);
            SBAR();
        }
    }

    // epilogue
#pragma unroll
    for (int m = 0; m < 8; m++) {
#pragma unroll
        for (int n = 0; n < 2; n++) {
#pragma unroll
            for (int r = 0; r < 4; r++) {
                int row = bm * 256 + wm * 128 + m * 16 + g * 4 + r;
                int col = bn * 128 + wn * 32 + n * 16 + r16;
                float v = acc[m * 2 + n][r] + bias[col];
                if (GELU) v = 0.5f * v * (1.0f + erff(v * 0.70710678118654752f));
                if (BF16OUT) cb[(size_t)row * N + col] = f2b(v);
                else cf[(size_t)row * N + col] = v;
            }
        }
    }
}

// ---------------- flash attention (swapped-QK^T, KBLK=64, MFMA row-sum) ----------------
__global__ __launch_bounds__(256) void attn_kernel(const u16* __restrict__ qkv, const int* __restrict__ mask,
                                                   u16* __restrict__ ctx) {
    const int tid = threadIdx.x, wid = tid >> 6, lane = tid & 63;
    const int r16 = lane & 15, g = lane >> 4;
    const int h = blockIdx.y, b = blockIdx.z;
    const size_t baserow = (size_t)b * 2048;
    const int q0 = blockIdx.x * 64;

    __shared__ __align__(16) u16 Ks[64 * 64];
    __shared__ __align__(16) u16 Vs[64 * 64];
    __shared__ __align__(16) float mb[64];

    const float SCALE = 0.18033688011112042f;   // 0.125 * log2(e)
    const float MNEG = -6.196328018e9f;         // -2^32 * log2(e)
    const s16x4 ONES = {(short)0x3F80, (short)0x3F80, (short)0x3F80, (short)0x3F80};

    short8 qf0, qf1;
    {
        const u16* qp = qkv + (baserow + q0 + wid * 16 + r16) * 3072 + h * 64 + g * 8;
        qf0 = *(const short8*)qp;
        qf1 = *(const short8*)(qp + 32);
    }

    const int L = lane;
    const int kchunk = (L & 7) ^ (L >> 3);
    const u16* kg0 = qkv + (baserow + wid * 16 + (L >> 3)) * 3072 + 1024 + h * 64 + kchunk * 8;
    const u16* kg1 = kg0 + (size_t)8 * 3072;
    u16* kl0 = &Ks[wid * 1024];
    u16* kl1 = &Ks[wid * 1024 + 512];
    const u16* vg0 = qkv + (baserow + wid * 16 + ((L & 31) >> 1)) * 3072 + 2048 + h * 64
                     + ((L >> 5) * 16 + (L & 1) * 8);
    const u16* vg1 = vg0 + 32;
    u16* vl0 = &Vs[wid * 1024];
    u16* vl1 = &Vs[wid * 1024 + 512];
    const unsigned vaddr = (unsigned)(unsigned long long)&Vs[0] + (unsigned)(r16 * 2 + g * 128);

    f32x4 Ot[4];
#pragma unroll
    for (int dt = 0; dt < 4; dt++) Ot[dt] = (f32x4){0.f, 0.f, 0.f, 0.f};
    f32x4 Osum = (f32x4){0.f, 0.f, 0.f, 0.f};   // denominator via ones-column MFMA
    float mrun = -1e30f;

    for (int kt = 0; kt < 2048; kt += 64) {
        const size_t go = (size_t)kt * 3072;
        gl_lds16(kg0 + go, kl0);
        gl_lds16(kg1 + go, kl1);
        gl_lds16(vg0 + go, vl0);
        gl_lds16(vg1 + go, vl1);
        if (tid < 64) mb[tid] = mask[baserow + kt + tid] ? MNEG : 0.0f;
        __syncthreads();

        // S^T tiles: z[t] = K_tile(t) x Q  -> lane holds S[t*16+4g+j][q=r16]
        f32x4 z[4];
        __builtin_amdgcn_s_setprio(1);
#pragma unroll
        for (int t = 0; t < 4; t++) {
            const int row = t * 16 + r16;
            const int swz = row & 7;
            short8 a0 = *(const short8*)&Ks[row * 64 + ((g ^ swz) * 8)];
            short8 a1 = *(const short8*)&Ks[row * 64 + (((4 + g) ^ swz) * 8)];
            f32x4 zz = (f32x4){0.f, 0.f, 0.f, 0.f};
            zz = MFMA32(a0, qf0, zz);
            zz = MFMA32(a1, qf1, zz);
            z[t] = zz;
        }
        __builtin_amdgcn_s_setprio(0);

        f32x4 sv[4];
#pragma unroll
        for (int t = 0; t < 4; t++) {
            f32x4 mbv = *(const f32x4*)&mb[t * 16 + g * 4];
            sv[t] = z[t] * SCALE + mbv;
        }

        // row max via v_max3 tree + 2 cross-group shfls
        float m0 = max3f(sv[0][0], sv[0][1], sv[0][2]);
        float m1 = max3f(sv[0][3], sv[1][0], sv[1][1]);
        float m2 = max3f(sv[1][2], sv[1][3], sv[2][0]);
        float m3 = max3f(sv[2][1], sv[2][2], sv[2][3]);
        float m4 = max3f(sv[3][0], sv[3][1], sv[3][2]);
        float pmax = fmaxf(max3f(m0, m1, m2), max3f(m3, m4, sv[3][3]));
        pmax = fmaxf(pmax, __shfl_xor(pmax, 16));
        pmax = fmaxf(pmax, __shfl_xor(pmax, 32));

        // defer-max (THR = 11.5 in log2 domain ~= 8 nats)
        if (!__all(pmax - mrun <= 11.5f)) {
            float mnew = fmaxf(mrun, pmax);
            float alpha = exp2f(mrun - mnew);
            mrun = mnew;
            Osum *= alpha;
#pragma unroll
            for (int dt = 0; dt < 4; dt++) Ot[dt] *= alpha;
        }

        // p = 2^(s'-m), pack via v_cvt_pk_bf16_f32 (no explicit row-sum: MFMA does it)
        s16x4 pb[4];
#pragma unroll
        for (int t = 0; t < 4; t++) {
            f32x4 d = sv[t] - mrun;
            float p0 = exp2f(d[0]), p1 = exp2f(d[1]), p2 = exp2f(d[2]), p3 = exp2f(d[3]);
            unsigned lo, hi;
            asm("v_cvt_pk_bf16_f32 %0, %1, %2" : "=v"(lo) : "v"(p0), "v"(p1));
            asm("v_cvt_pk_bf16_f32 %0, %1, %2" : "=v"(hi) : "v"(p2), "v"(p3));
            uint2 u; u.x = lo; u.y = hi;
            pb[t] = __builtin_bit_cast(s16x4, u);
        }

        // PV: O^T[dt] += V^T_frag(t,dt) x P_frag(t); Osum += 1^T x P_frag(t)
        s16x4 vf[4][4];
#pragma unroll
        for (int t = 0; t < 4; t++)
#pragma unroll
            for (int dt = 0; dt < 4; dt++)
                asm volatile("ds_read_b64_tr_b16 %0, %1"
                             : "=v"(vf[t][dt])
                             : "v"(vaddr + (unsigned)((t * 4 + dt) * 512)));
        asm volatile("s_waitcnt lgkmcnt(0)" ::: "memory");
        __builtin_amdgcn_sched_barrier(0);
        __builtin_amdgcn_s_setprio(1);
#pragma unroll
        for (int t = 0; t < 4; t++) {
#pragma unroll
            for (int dt = 0; dt < 4; dt++) Ot[dt] = MFMA16(vf[t][dt], pb[t], Ot[dt]);
            Osum = MFMA16(ONES, pb[t], Osum);
        }
        __builtin_amdgcn_s_setprio(0);
        __syncthreads();
    }

    const float rl = 1.0f / Osum[0];
    u16* cp = ctx + (baserow + q0 + wid * 16 + r16) * 1024 + h * 64 + g * 4;
#pragma unroll
    for (int dt = 0; dt < 4; dt++) {
        ushort4 o4;
        o4.x = f2b(Ot[dt][0] * rl);
        o4.y = f2b(Ot[dt][1] * rl);
        o4.z = f2b(Ot[dt][2] * rl);
        o4.w = f2b(Ot[dt][3] * rl);
        *(ushort4*)(cp + dt * 16) = o4;
    }
}

// ---------------- fused residual + layernorm ----------------
__global__ __launch_bounds__(256) void ln_kernel(const float* __restrict__ a, const float* __restrict__ res,
                                                 const float* __restrict__ gamma, const float* __restrict__ beta,
                                                 float* __restrict__ outf, u16* __restrict__ outb) {
    const int row = blockIdx.x, tid = threadIdx.x;
    const size_t base = (size_t)row * 1024 + tid * 4;
    float4 va = *(const float4*)(a + base);
    float4 vr = *(const float4*)(res + base);
    float x0 = va.x + vr.x, x1 = va.y + vr.y, x2 = va.z + vr.z, x3 = va.w + vr.w;
    float s = x0 + x1 + x2 + x3;
    float ss = x0 * x0 + x1 * x1 + x2 * x2 + x3 * x3;
#pragma unroll
    for (int m = 1; m < 64; m <<= 1) { s += __shfl_xor(s, m, 64); ss += __shfl_xor(ss, m, 64); }
    __shared__ float red[8];
    if ((tid & 63) == 0) { red[tid >> 6] = s; red[4 + (tid >> 6)] = ss; }
    __syncthreads();
    s = red[0] + red[1] + red[2] + red[3];
    ss = red[4] + red[5] + red[6] + red[7];
    float mu = s * (1.0f / 1024.0f);
    float var = ss * (1.0f / 1024.0f) - mu * mu;
    float rstd = rsqrtf(var + 1e-5f);
    float4 g4 = *(const float4*)(gamma + tid * 4);
    float4 b4 = *(const float4*)(beta + tid * 4);
    float y0 = (x0 - mu) * rstd * g4.x + b4.x;
    float y1 = (x1 - mu) * rstd * g4.y + b4.y;
    float y2 = (x2 - mu) * rstd * g4.z + b4.z;
    float y3 = (x3 - mu) * rstd * g4.w + b4.w;
    *(float4*)(outf + base) = make_float4(y0, y1, y2, y3);
    if (outb) {
        ushort4 ob;
        ob.x = f2b(y0); ob.y = f2b(y1); ob.z = f2b(y2); ob.w = f2b(y3);
        *(ushort4*)(outb + base) = ob;
    }
}

extern "C" void kernel_launch(void* const* d_in, const int* in_sizes, int n_in, void* d_out, int out_size,
                              void* d_ws, size_t ws_size, hipStream_t stream) {
    const float* x = (const float*)d_in[0];
    const int* mask = (const int*)d_in[1];
    const float* Wq = (const float*)d_in[2];
    const float* bq = (const float*)d_in[3];
    const float* Wk = (const float*)d_in[4];
    const float* bk = (const float*)d_in[5];
    const float* Wv = (const float*)d_in[6];
    const float* bv = (const float*)d_in[7];
    const float* Wo = (const float*)d_in[8];
    const float* bo = (const float*)d_in[9];
    const float* ln1s = (const float*)d_in[10];
    const float* ln1b = (const float*)d_in[11];
    const float* W1 = (const float*)d_in[12];
    const float* b1 = (const float*)d_in[13];
    const float* W2 = (const float*)d_in[14];
    const float* b2 = (const float*)d_in[15];
    const float* ln2s = (const float*)d_in[16];
    const float* ln2b = (const float*)d_in[17];
    float* out = (float*)d_out;
    char* ws = (char*)d_ws;

    const size_t MB = 1024 * 1024;
    u16* XB = (u16*)(ws + 0);                 // x bf16 [8192][1024]
    u16* WTq = (u16*)(ws + 16 * MB);          // [Wq^T;Wk^T;Wv^T] = Bt[3072][1024]
    u16* WTk = WTq + 1024 * 1024;
    u16* WTv = WTk + 1024 * 1024;
    u16* WTo = WTv + 1024 * 1024;             // Wo^T [1024][1024]
    u16* WT1 = WTo + 1024 * 1024;             // W1^T [4096][1024]
    u16* WT2 = WT1 + 4096 * 1024;             // W2^T [1024][4096]
    float* BIAS = (float*)(ws + 40 * MB);
    u16* QKV = (u16*)(ws + 41 * MB);          // [8192][3072] bf16
    u16* CTX = (u16*)(ws + 0);                // [8192][1024] bf16 (reuse XB)
    float* ATT = (float*)(ws + 41 * MB);      // fp32 (reuse QKV)
    float* Hbuf = (float*)(ws + 73 * MB);
    u16* HB = (u16*)(ws + 105 * MB);
    u16* MLP1 = (u16*)(ws + 121 * MB);        // [8192][4096] bf16
    float* MLP2 = (float*)(ws + 41 * MB);     // fp32 (reuse ATT)

    dim3 tb(32, 8);
    cast_bf16<<<8192, 256, 0, stream>>>(x, XB, 8192 * 1024);
    transpose_cast<<<dim3(32, 32), tb, 0, stream>>>(Wq, WTq, 1024, 1024);
    transpose_cast<<<dim3(32, 32), tb, 0, stream>>>(Wk, WTk, 1024, 1024);
    transpose_cast<<<dim3(32, 32), tb, 0, stream>>>(Wv, WTv, 1024, 1024);
    transpose_cast<<<dim3(32, 32), tb, 0, stream>>>(Wo, WTo, 1024, 1024);
    transpose_cast<<<dim3(128, 32), tb, 0, stream>>>(W1, WT1, 1024, 4096);
    transpose_cast<<<dim3(32, 128), tb, 0, stream>>>(W2, WT2, 4096, 1024);
    pack_bias<<<36, 256, 0, stream>>>(bq, bk, bv, bo, b1, b2, BIAS);

    // QKV: grid 32*24=768
    gemm8p<false, true><<<768, 512, 0, stream>>>(XB, WTq, BIAS, nullptr, QKV, 8192, 3072, 1024);
    attn_kernel<<<dim3(32, 16, 4), 256, 0, stream>>>(QKV, mask, CTX);
    // Wo: grid 32*8=256
    gemm8p<false, false><<<256, 512, 0, stream>>>(CTX, WTo, BIAS + 3072, ATT, nullptr, 8192, 1024, 1024);
    ln_kernel<<<8192, 256, 0, stream>>>(ATT, x, ln1s, ln1b, Hbuf, HB);
    // MLP1: grid 32*32=1024
    gemm8p<true, true><<<1024, 512, 0, stream>>>(HB, WT1, BIAS + 4096, nullptr, MLP1, 8192, 4096, 1024);
    // MLP2: grid 32*8=256
    gemm8p<false, false><<<256, 512, 0, stream>>>(MLP1, WT2, BIAS + 8192, MLP2, nullptr, 8192, 1024, 4096);
    ln_kernel<<<8192, 256, 0, stream>>>(MLP2, Hbuf, ln2s, ln2b, out, nullptr);
}

// Round 7
// 528.985 us; speedup vs baseline: 1.1582x; 1.1582x over previous
//
#include <hip/hip_runtime.h>
#include <hip/hip_bf16.h>

typedef __attribute__((ext_vector_type(8))) short short8;
typedef __attribute__((ext_vector_type(4))) short s16x4;
typedef __attribute__((ext_vector_type(4))) float f32x4;
typedef unsigned short u16;

#define DEV __device__ __forceinline__
#define MFMA32(a, b, c) __builtin_amdgcn_mfma_f32_16x16x32_bf16(a, b, c, 0, 0, 0)
#define MFMA16(a, b, c) __builtin_amdgcn_mfma_f32_16x16x16bf16_1k(a, b, c, 0, 0, 0)

DEV u16 f2b(float f) {
    __hip_bfloat16 h = __float2bfloat16(f);
    return __builtin_bit_cast(unsigned short, h);
}

DEV float max3f(float a, float b, float c) {
    float d;
    asm("v_max3_f32 %0, %1, %2, %3" : "=v"(d) : "v"(a), "v"(b), "v"(c));
    return d;
}

DEV void gl_lds16(const u16* g, u16* l) {
    __builtin_amdgcn_global_load_lds((const unsigned int*)g, (unsigned int*)l, 16, 0, 0);
}

// ---------------- cast x: fp32 -> bf16 ----------------
__global__ __launch_bounds__(256) void cast_bf16(const float* __restrict__ in, u16* __restrict__ out, int n) {
    int i = (blockIdx.x * 256 + threadIdx.x) * 4;
    if (i < n) {
        float4 v = *(const float4*)(in + i);
        ushort4 o;
        o.x = f2b(v.x); o.y = f2b(v.y); o.z = f2b(v.z); o.w = f2b(v.w);
        *(ushort4*)(out + i) = o;
    }
}

// ---------------- transpose + cast: W[R][C] fp32 -> Wt[C][R] bf16 ----------------
__global__ __launch_bounds__(256) void transpose_cast(const float* __restrict__ in, u16* __restrict__ out,
                                                      int R, int C) {
    __shared__ float t[32][33];
    int bx = blockIdx.x * 32;
    int by = blockIdx.y * 32;
    int tx = threadIdx.x, ty = threadIdx.y;  // (32, 8)
#pragma unroll
    for (int i = 0; i < 32; i += 8) t[ty + i][tx] = in[(size_t)(by + ty + i) * C + bx + tx];
    __syncthreads();
#pragma unroll
    for (int i = 0; i < 32; i += 8) out[(size_t)(bx + ty + i) * R + by + tx] = f2b(t[tx][ty + i]);
}

// ---------------- pack biases into one buffer ----------------
__global__ __launch_bounds__(256) void pack_bias(const float* __restrict__ bq, const float* __restrict__ bk,
                                                 const float* __restrict__ bv, const float* __restrict__ bo,
                                                 const float* __restrict__ b1, const float* __restrict__ b2,
                                                 float* __restrict__ out) {
    int i = blockIdx.x * 256 + threadIdx.x;
    if (i >= 9216) return;
    float v;
    if (i < 1024) v = bq[i];
    else if (i < 2048) v = bk[i - 1024];
    else if (i < 3072) v = bv[i - 2048];
    else if (i < 4096) v = bo[i - 3072];
    else if (i < 8192) v = b1[i - 4096];
    else v = b2[i - 8192];
    out[i] = v;
}

// ---------------- GEMM: C[M][N] = A[M][K] * Bt[N][K]^T + bias, optional GELU ----------------
// m97 structure (proven best here): 128x128 tile, BK=32, 256 threads (4 waves, 2x2),
// global_load_lds width 16, 2 barriers per K-step, ~3 blocks/CU for implicit overlap.
template <bool GELU, bool BF16OUT>
__global__ __launch_bounds__(256) void gemm_bt(const u16* __restrict__ A, const u16* __restrict__ B,
                                               const float* __restrict__ bias, float* __restrict__ cf,
                                               u16* __restrict__ cb, int M, int N, int K) {
    __shared__ __align__(16) u16 As[128 * 32];
    __shared__ __align__(16) u16 Bs[128 * 32];
    const int tid = threadIdx.x;
    const int wid = tid >> 6, lane = tid & 63;
    const int wr = wid >> 1, wc = wid & 1;
    const int m0 = blockIdx.x * 128, n0 = blockIdx.y * 128;
    const int r16 = lane & 15, g = lane >> 4;
    const int lrow = lane >> 2, lk = (lane & 3) * 8;

    f32x4 acc[4][4];
#pragma unroll
    for (int i = 0; i < 4; i++)
#pragma unroll
        for (int j = 0; j < 4; j++) acc[i][j] = (f32x4){0.f, 0.f, 0.f, 0.f};

    const u16* ga = A + (size_t)(m0 + wid * 32 + lrow) * K + lk;
    const u16* gb = B + (size_t)(n0 + wid * 32 + lrow) * K + lk;
    u16* lA0 = &As[(wid * 32) * 32];
    u16* lA1 = &As[(wid * 32 + 16) * 32];
    u16* lB0 = &Bs[(wid * 32) * 32];
    u16* lB1 = &Bs[(wid * 32 + 16) * 32];

    for (int kt = 0; kt < K; kt += 32) {
        gl_lds16(ga + kt, lA0);
        gl_lds16(ga + (size_t)16 * K + kt, lA1);
        gl_lds16(gb + kt, lB0);
        gl_lds16(gb + (size_t)16 * K + kt, lB1);
        __syncthreads();
        short8 af[4], bfr[4];
#pragma unroll
        for (int i = 0; i < 4; i++) af[i] = *(const short8*)&As[(wr * 64 + i * 16 + r16) * 32 + g * 8];
#pragma unroll
        for (int j = 0; j < 4; j++) bfr[j] = *(const short8*)&Bs[(wc * 64 + j * 16 + r16) * 32 + g * 8];
#pragma unroll
        for (int i = 0; i < 4; i++)
#pragma unroll
            for (int j = 0; j < 4; j++) acc[i][j] = MFMA32(af[i], bfr[j], acc[i][j]);
        __syncthreads();
    }

#pragma unroll
    for (int i = 0; i < 4; i++) {
#pragma unroll
        for (int j = 0; j < 4; j++) {
#pragma unroll
            for (int r = 0; r < 4; r++) {
                int row = m0 + wr * 64 + i * 16 + g * 4 + r;
                int col = n0 + wc * 64 + j * 16 + r16;
                float v = acc[i][j][r] + bias[col];
                if (GELU) v = 0.5f * v * (1.0f + erff(v * 0.70710678118654752f));
                if (BF16OUT) cb[(size_t)row * N + col] = f2b(v);
                else cf[(size_t)row * N + col] = v;
            }
        }
    }
}

// ---------------- flash attention (swapped-QK^T, KBLK=64, MFMA row-sum) ----------------
__global__ __launch_bounds__(256) void attn_kernel(const u16* __restrict__ qkv, const int* __restrict__ mask,
                                                   u16* __restrict__ ctx) {
    const int tid = threadIdx.x, wid = tid >> 6, lane = tid & 63;
    const int r16 = lane & 15, g = lane >> 4;
    const int h = blockIdx.y, b = blockIdx.z;
    const size_t baserow = (size_t)b * 2048;
    const int q0 = blockIdx.x * 64;

    __shared__ __align__(16) u16 Ks[64 * 64];
    __shared__ __align__(16) u16 Vs[64 * 64];
    __shared__ __align__(16) float mb[64];

    const float SCALE = 0.18033688011112042f;   // 0.125 * log2(e)
    const float MNEG = -6.196328018e9f;         // -2^32 * log2(e)
    const s16x4 ONES = {(short)0x3F80, (short)0x3F80, (short)0x3F80, (short)0x3F80};

    short8 qf0, qf1;
    {
        const u16* qp = qkv + (baserow + q0 + wid * 16 + r16) * 3072 + h * 64 + g * 8;
        qf0 = *(const short8*)qp;
        qf1 = *(const short8*)(qp + 32);
    }

    const int L = lane;
    const int kchunk = (L & 7) ^ (L >> 3);
    const u16* kg0 = qkv + (baserow + wid * 16 + (L >> 3)) * 3072 + 1024 + h * 64 + kchunk * 8;
    const u16* kg1 = kg0 + (size_t)8 * 3072;
    u16* kl0 = &Ks[wid * 1024];
    u16* kl1 = &Ks[wid * 1024 + 512];
    const u16* vg0 = qkv + (baserow + wid * 16 + ((L & 31) >> 1)) * 3072 + 2048 + h * 64
                     + ((L >> 5) * 16 + (L & 1) * 8);
    const u16* vg1 = vg0 + 32;
    u16* vl0 = &Vs[wid * 1024];
    u16* vl1 = &Vs[wid * 1024 + 512];
    const unsigned vaddr = (unsigned)(unsigned long long)&Vs[0] + (unsigned)(r16 * 2 + g * 128);

    f32x4 Ot[4];
#pragma unroll
    for (int dt = 0; dt < 4; dt++) Ot[dt] = (f32x4){0.f, 0.f, 0.f, 0.f};
    f32x4 Osum = (f32x4){0.f, 0.f, 0.f, 0.f};   // denominator via ones-column MFMA
    float mrun = -1e30f;

    for (int kt = 0; kt < 2048; kt += 64) {
        const size_t go = (size_t)kt * 3072;
        gl_lds16(kg0 + go, kl0);
        gl_lds16(kg1 + go, kl1);
        gl_lds16(vg0 + go, vl0);
        gl_lds16(vg1 + go, vl1);
        if (tid < 64) mb[tid] = mask[baserow + kt + tid] ? MNEG : 0.0f;
        __syncthreads();

        // S^T tiles: z[t] = K_tile(t) x Q  -> lane holds S[t*16+4g+j][q=r16]
        f32x4 z[4];
        __builtin_amdgcn_s_setprio(1);
#pragma unroll
        for (int t = 0; t < 4; t++) {
            const int row = t * 16 + r16;
            const int swz = row & 7;
            short8 a0 = *(const short8*)&Ks[row * 64 + ((g ^ swz) * 8)];
            short8 a1 = *(const short8*)&Ks[row * 64 + (((4 + g) ^ swz) * 8)];
            f32x4 zz = (f32x4){0.f, 0.f, 0.f, 0.f};
            zz = MFMA32(a0, qf0, zz);
            zz = MFMA32(a1, qf1, zz);
            z[t] = zz;
        }
        __builtin_amdgcn_s_setprio(0);

        f32x4 sv[4];
#pragma unroll
        for (int t = 0; t < 4; t++) {
            f32x4 mbv = *(const f32x4*)&mb[t * 16 + g * 4];
            sv[t] = z[t] * SCALE + mbv;
        }

        // row max via v_max3 tree + 2 cross-group shfls
        float m0 = max3f(sv[0][0], sv[0][1], sv[0][2]);
        float m1 = max3f(sv[0][3], sv[1][0], sv[1][1]);
        float m2 = max3f(sv[1][2], sv[1][3], sv[2][0]);
        float m3 = max3f(sv[2][1], sv[2][2], sv[2][3]);
        float m4 = max3f(sv[3][0], sv[3][1], sv[3][2]);
        float pmax = fmaxf(max3f(m0, m1, m2), max3f(m3, m4, sv[3][3]));
        pmax = fmaxf(pmax, __shfl_xor(pmax, 16));
        pmax = fmaxf(pmax, __shfl_xor(pmax, 32));

        // defer-max (THR = 11.5 in log2 domain ~= 8 nats)
        if (!__all(pmax - mrun <= 11.5f)) {
            float mnew = fmaxf(mrun, pmax);
            float alpha = exp2f(mrun - mnew);
            mrun = mnew;
            Osum *= alpha;
#pragma unroll
            for (int dt = 0; dt < 4; dt++) Ot[dt] *= alpha;
        }

        // p = 2^(s'-m), pack via v_cvt_pk_bf16_f32 (row-sum comes from ones-MFMA)
        s16x4 pb[4];
#pragma unroll
        for (int t = 0; t < 4; t++) {
            f32x4 d = sv[t] - mrun;
            float p0 = exp2f(d[0]), p1 = exp2f(d[1]), p2 = exp2f(d[2]), p3 = exp2f(d[3]);
            unsigned lo, hi;
            asm("v_cvt_pk_bf16_f32 %0, %1, %2" : "=v"(lo) : "v"(p0), "v"(p1));
            asm("v_cvt_pk_bf16_f32 %0, %1, %2" : "=v"(hi) : "v"(p2), "v"(p3));
            uint2 u; u.x = lo; u.y = hi;
            pb[t] = __builtin_bit_cast(s16x4, u);
        }

        // PV: O^T[dt] += V^T_frag(t,dt) x P_frag(t); Osum += 1^T x P_frag(t)
        s16x4 vf[4][4];
#pragma unroll
        for (int t = 0; t < 4; t++)
#pragma unroll
            for (int dt = 0; dt < 4; dt++)
                asm volatile("ds_read_b64_tr_b16 %0, %1"
                             : "=v"(vf[t][dt])
                             : "v"(vaddr + (unsigned)((t * 4 + dt) * 512)));
        asm volatile("s_waitcnt lgkmcnt(0)" ::: "memory");
        __builtin_amdgcn_sched_barrier(0);
        __builtin_amdgcn_s_setprio(1);
#pragma unroll
        for (int t = 0; t < 4; t++) {
#pragma unroll
            for (int dt = 0; dt < 4; dt++) Ot[dt] = MFMA16(vf[t][dt], pb[t], Ot[dt]);
            Osum = MFMA16(ONES, pb[t], Osum);
        }
        __builtin_amdgcn_s_setprio(0);
        __syncthreads();
    }

    const float rl = 1.0f / Osum[0];
    u16* cp = ctx + (baserow + q0 + wid * 16 + r16) * 1024 + h * 64 + g * 4;
#pragma unroll
    for (int dt = 0; dt < 4; dt++) {
        ushort4 o4;
        o4.x = f2b(Ot[dt][0] * rl);
        o4.y = f2b(Ot[dt][1] * rl);
        o4.z = f2b(Ot[dt][2] * rl);
        o4.w = f2b(Ot[dt][3] * rl);
        *(ushort4*)(cp + dt * 16) = o4;
    }
}

// ---------------- fused residual + layernorm ----------------
__global__ __launch_bounds__(256) void ln_kernel(const float* __restrict__ a, const float* __restrict__ res,
                                                 const float* __restrict__ gamma, const float* __restrict__ beta,
                                                 float* __restrict__ outf, u16* __restrict__ outb) {
    const int row = blockIdx.x, tid = threadIdx.x;
    const size_t base = (size_t)row * 1024 + tid * 4;
    float4 va = *(const float4*)(a + base);
    float4 vr = *(const float4*)(res + base);
    float x0 = va.x + vr.x, x1 = va.y + vr.y, x2 = va.z + vr.z, x3 = va.w + vr.w;
    float s = x0 + x1 + x2 + x3;
    float ss = x0 * x0 + x1 * x1 + x2 * x2 + x3 * x3;
#pragma unroll
    for (int m = 1; m < 64; m <<= 1) { s += __shfl_xor(s, m, 64); ss += __shfl_xor(ss, m, 64); }
    __shared__ float red[8];
    if ((tid & 63) == 0) { red[tid >> 6] = s; red[4 + (tid >> 6)] = ss; }
    __syncthreads();
    s = red[0] + red[1] + red[2] + red[3];
    ss = red[4] + red[5] + red[6] + red[7];
    float mu = s * (1.0f / 1024.0f);
    float var = ss * (1.0f / 1024.0f) - mu * mu;
    float rstd = rsqrtf(var + 1e-5f);
    float4 g4 = *(const float4*)(gamma + tid * 4);
    float4 b4 = *(const float4*)(beta + tid * 4);
    float y0 = (x0 - mu) * rstd * g4.x + b4.x;
    float y1 = (x1 - mu) * rstd * g4.y + b4.y;
    float y2 = (x2 - mu) * rstd * g4.z + b4.z;
    float y3 = (x3 - mu) * rstd * g4.w + b4.w;
    *(float4*)(outf + base) = make_float4(y0, y1, y2, y3);
    if (outb) {
        ushort4 ob;
        ob.x = f2b(y0); ob.y = f2b(y1); ob.z = f2b(y2); ob.w = f2b(y3);
        *(ushort4*)(outb + base) = ob;
    }
}

extern "C" void kernel_launch(void* const* d_in, const int* in_sizes, int n_in, void* d_out, int out_size,
                              void* d_ws, size_t ws_size, hipStream_t stream) {
    const float* x = (const float*)d_in[0];
    const int* mask = (const int*)d_in[1];
    const float* Wq = (const float*)d_in[2];
    const float* bq = (const float*)d_in[3];
    const float* Wk = (const float*)d_in[4];
    const float* bk = (const float*)d_in[5];
    const float* Wv = (const float*)d_in[6];
    const float* bv = (const float*)d_in[7];
    const float* Wo = (const float*)d_in[8];
    const float* bo = (const float*)d_in[9];
    const float* ln1s = (const float*)d_in[10];
    const float* ln1b = (const float*)d_in[11];
    const float* W1 = (const float*)d_in[12];
    const float* b1 = (const float*)d_in[13];
    const float* W2 = (const float*)d_in[14];
    const float* b2 = (const float*)d_in[15];
    const float* ln2s = (const float*)d_in[16];
    const float* ln2b = (const float*)d_in[17];
    float* out = (float*)d_out;
    char* ws = (char*)d_ws;

    const size_t MB = 1024 * 1024;
    u16* XB = (u16*)(ws + 0);                 // x bf16 [8192][1024]
    u16* WTq = (u16*)(ws + 16 * MB);          // [Wq^T;Wk^T;Wv^T] = Bt[3072][1024]
    u16* WTk = WTq + 1024 * 1024;
    u16* WTv = WTk + 1024 * 1024;
    u16* WTo = WTv + 1024 * 1024;             // Wo^T [1024][1024]
    u16* WT1 = WTo + 1024 * 1024;             // W1^T [4096][1024]
    u16* WT2 = WT1 + 4096 * 1024;             // W2^T [1024][4096]
    float* BIAS = (float*)(ws + 40 * MB);
    u16* QKV = (u16*)(ws + 41 * MB);          // [8192][3072] bf16
    u16* CTX = (u16*)(ws + 0);                // [8192][1024] bf16 (reuse XB)
    float* ATT = (float*)(ws + 41 * MB);      // fp32 (reuse QKV)
    float* Hbuf = (float*)(ws + 73 * MB);
    u16* HB = (u16*)(ws + 105 * MB);
    u16* MLP1 = (u16*)(ws + 121 * MB);        // [8192][4096] bf16
    float* MLP2 = (float*)(ws + 41 * MB);     // fp32 (reuse ATT)

    dim3 tb(32, 8);
    cast_bf16<<<8192, 256, 0, stream>>>(x, XB, 8192 * 1024);
    transpose_cast<<<dim3(32, 32), tb, 0, stream>>>(Wq, WTq, 1024, 1024);
    transpose_cast<<<dim3(32, 32), tb, 0, stream>>>(Wk, WTk, 1024, 1024);
    transpose_cast<<<dim3(32, 32), tb, 0, stream>>>(Wv, WTv, 1024, 1024);
    transpose_cast<<<dim3(32, 32), tb, 0, stream>>>(Wo, WTo, 1024, 1024);
    transpose_cast<<<dim3(128, 32), tb, 0, stream>>>(W1, WT1, 1024, 4096);
    transpose_cast<<<dim3(32, 128), tb, 0, stream>>>(W2, WT2, 4096, 1024);
    pack_bias<<<36, 256, 0, stream>>>(bq, bk, bv, bo, b1, b2, BIAS);

    // QKV projection: [8192][3072]
    gemm_bt<false, true><<<dim3(64, 24), 256, 0, stream>>>(XB, WTq, BIAS, nullptr, QKV, 8192, 3072, 1024);
    attn_kernel<<<dim3(32, 16, 4), 256, 0, stream>>>(QKV, mask, CTX);
    // output projection (fp32 out)
    gemm_bt<false, false><<<dim3(64, 8), 256, 0, stream>>>(CTX, WTo, BIAS + 3072, ATT, nullptr, 8192, 1024, 1024);
    ln_kernel<<<8192, 256, 0, stream>>>(ATT, x, ln1s, ln1b, Hbuf, HB);
    // mlp1 = gelu(h @ W1 + b1)
    gemm_bt<true, true><<<dim3(64, 32), 256, 0, stream>>>(HB, WT1, BIAS + 4096, nullptr, MLP1, 8192, 4096, 1024);
    // mlp2 = mlp1 @ W2 + b2
    gemm_bt<false, false><<<dim3(64, 8), 256, 0, stream>>>(MLP1, WT2, BIAS + 8192, MLP2, nullptr, 8192, 1024, 4096);
    ln_kernel<<<8192, 256, 0, stream>>>(MLP2, Hbuf, ln2s, ln2b, out, nullptr);
}